// Round 13
// baseline (965.834 us; speedup 1.0000x reference)
//
#include <hip/hip_runtime.h>
#include <stdint.h>

typedef unsigned short u16;
typedef __bf16 bf16x8 __attribute__((ext_vector_type(8)));
typedef unsigned short u16x8 __attribute__((ext_vector_type(8)));
typedef float f32x4 __attribute__((ext_vector_type(4)));

#define N_NODES 50000
#define N_EDGES 800000

enum : uint32_t {
  WS_WT_E1 = 0u,          // [256][256] bf16 plain W_e1^T (k<128 src part, k>=128 dst part)
  WS_WT_E2 = 131072u,     // FRAG layout [8][16][64][8] bf16 (W_e2 B-fragments)
  WS_WT_C1 = 262144u,     // FRAG layout (W_c1)
  WS_WT_N1 = 393216u,     // [256][384] bf16 plain
  WS_WT_N2 = 589824u,     // [128][256] bf16 plain
  WS_WRAD  = 655360u,     // f32[256]
  WS_WC2   = 656384u,     // f32[256]
  WS_B_E1  = 657408u,
  WS_B_E2  = 658432u,
  WS_B_C1  = 659456u,
  WS_B_N1  = 660480u,
  WS_B_N2  = 661504u,
  WS_GAMMA = 662016u,
  WS_BETA  = 662528u,
  WS_SCALE = 663040u,
  WS_SHIFT = 663552u,
  WS_STAT  = 664064u,
  WS_FLAG  = 665600u,
  WS_DEG   = 1048576u,    // int[50000]
  WS_OFF   = 1248576u,    // int[50001]
  WS_BSUM  = 1448704u,
  WS_BPRE  = 1449728u,
  WS_CUR   = 1450752u,    // int[50000]
  WS_EID   = 1650752u,    // int[800000]         ends 4850752
  WS_XSUM  = 4850752u,    // f32[50000*3]
  WS_CF    = 5450752u,    // f32[50000*3]
  WS_NF    = 6050752u,    // bf16[50000*128]     ends 18850752
  WS_HN    = 18850752u,   // f32[50000*256]      ends 70050752
  WS_PA    = 70050752u,   // bf16[50048*256] (PRE) / hpre alias
  WS_PB    = 95675328u,   // bf16[50048*256] (PRE only)
  WS_PRE_END = 121299904u
};

__device__ __forceinline__ float b2f(u16 u){ uint32_t x=((uint32_t)u)<<16; float f; __builtin_memcpy(&f,&x,4); return f; }
__device__ __forceinline__ u16 f2b(float f){ __bf16 h = (__bf16)f; return __builtin_bit_cast(unsigned short, h); }
__device__ __forceinline__ float silu_f(float x){
  return x * __builtin_amdgcn_rcpf(1.0f + __expf(-x));
}
__device__ __forceinline__ float ldin(const void* p, int i, int fl){
  return fl ? ((const float*)p)[i] : b2f(((const u16*)p)[i]);
}

// ---------------- dtype detect ----------------
__global__ void detect_k(const void* nf, int* flag){
  if (threadIdx.x == 0){
    const u16* p = (const u16*)nf;
    int cnt = 0;
    for (int i=0;i<128;i++){
      u16 u = p[2*i];
      int e = (u >> 7) & 0xFF;
      if (e >= 0x90) cnt++;
    }
    *flag = (cnt >= 8) ? 1 : 0;
  }
}

// ---------------- fused prep: cvt_nf | cvt_cf | weight prep | histo ----------------
__global__ void prep_all_k(const void* nf, const void* cd,
                           const void* We1, const void* be1, const void* We2, const void* be2,
                           const void* Wc1, const void* bc1, const void* Wc2,
                           const void* Wn1, const void* bn1, const void* Wn2, const void* bn2,
                           const void* gam, const void* bet,
                           const int* __restrict__ dst, int* __restrict__ deg,
                           char* ws, const int* flagp)
{
  const int b = blockIdx.x;
  const int fl = *flagp;
  if (b < 6250){
    int i = b*256 + threadIdx.x;
    if (i >= (N_NODES*128)/4) return;
    ushort4* out = (ushort4*)(ws + WS_NF);
    if (fl){
      const float4* p = (const float4*)nf;
      float4 v = p[i];
      ushort4 o; o.x=f2b(v.x); o.y=f2b(v.y); o.z=f2b(v.z); o.w=f2b(v.w);
      out[i] = o;
    } else {
      out[i] = ((const ushort4*)nf)[i];
    }
    return;
  }
  if (b < 6837){
    int i = (b-6250)*256 + threadIdx.x;
    if (i >= N_NODES*3) return;
    ((float*)(ws + WS_CF))[i] = ldin(cd, i, fl);
    return;
  }
  if (b < 8125){
    int g = (b-6837)*256 + threadIdx.x;
    if (g < 65536){ int n=g>>8,k=g&255; ((u16*)(ws+WS_WT_E1))[n*256+k]=f2b(ldin(We1,k*256+n,fl)); return; } g-=65536;
    if (g < 65536){
      int j=g&7, l=(g>>3)&63, nblk=(g>>9)&15, kk=g>>13;
      int n=nblk*16+(l&15), k=kk*32+((l>>4)&3)*8+j;
      ((u16*)(ws+WS_WT_E2))[g]=f2b(ldin(We2,k*256+n,fl)); return; } g-=65536;
    if (g < 65536){
      int j=g&7, l=(g>>3)&63, nblk=(g>>9)&15, kk=g>>13;
      int n=nblk*16+(l&15), k=kk*32+((l>>4)&3)*8+j;
      ((u16*)(ws+WS_WT_C1))[g]=f2b(ldin(Wc1,k*256+n,fl)); return; } g-=65536;
    if (g < 98304){ int n=g/384,k=g-n*384; ((u16*)(ws+WS_WT_N1))[n*384+k]=f2b(ldin(Wn1,k*256+n,fl)); return; } g-=98304;
    if (g < 32768){ int n=g>>8,k=g&255; ((u16*)(ws+WS_WT_N2))[n*256+k]=f2b(ldin(Wn2,k*128+n,fl)); return; } g-=32768;
    if (g < 256){ ((float*)(ws+WS_WRAD))[g]=ldin(We1,65536+g,fl); return; } g-=256;
    if (g < 256){ ((float*)(ws+WS_WC2))[g]=ldin(Wc2,g,fl); return; } g-=256;
    if (g < 256){ ((float*)(ws+WS_B_E1))[g]=ldin(be1,g,fl); return; } g-=256;
    if (g < 256){ ((float*)(ws+WS_B_E2))[g]=ldin(be2,g,fl); return; } g-=256;
    if (g < 256){ ((float*)(ws+WS_B_C1))[g]=ldin(bc1,g,fl); return; } g-=256;
    if (g < 256){ ((float*)(ws+WS_B_N1))[g]=ldin(bn1,g,fl); return; } g-=256;
    if (g < 128){ ((float*)(ws+WS_B_N2))[g]=ldin(bn2,g,fl); return; } g-=128;
    if (g < 128){ ((float*)(ws+WS_GAMMA))[g]=ldin(gam,g,fl); return; } g-=128;
    if (g < 128){ ((float*)(ws+WS_BETA))[g]=ldin(bet,g,fl); return; }
    return;
  }
  {
    int e = (b-8125)*256 + threadIdx.x;
    if (e < N_EDGES) atomicAdd(&deg[dst[e]], 1);
  }
}

// ---------------- CSR build ----------------
__global__ void scanA_k(const int* __restrict__ deg, int* __restrict__ off, int* __restrict__ bsum){
  int t = threadIdx.x; int i = blockIdx.x*256 + t;
  int lane = t & 63, w = t >> 6;
  int v = (i < N_NODES) ? deg[i] : 0;
  int x = v;
  #pragma unroll
  for (int d=1; d<64; d<<=1){ int o = __shfl_up(x, d, 64); if (lane >= d) x += o; }
  __shared__ int wt[4];
  if (lane == 63) wt[w] = x;
  __syncthreads();
  int add = 0;
  if (w > 0) add += wt[0];
  if (w > 1) add += wt[1];
  if (w > 2) add += wt[2];
  x += add;
  if (i < N_NODES) off[i] = x;
  if (t == 255) bsum[blockIdx.x] = x;
}

__global__ void scanB_k(const int* __restrict__ bsum, int* __restrict__ bpre, int* __restrict__ off){
  int t = threadIdx.x;
  int lane = t & 63, w = t >> 6;
  int v = (t < 196) ? bsum[t] : 0;
  int x = v;
  #pragma unroll
  for (int d=1; d<64; d<<=1){ int o = __shfl_up(x, d, 64); if (lane >= d) x += o; }
  __shared__ int wt[4];
  if (lane == 63) wt[w] = x;
  __syncthreads();
  int add = 0;
  if (w > 0) add += wt[0];
  if (w > 1) add += wt[1];
  if (w > 2) add += wt[2];
  x += add;
  if (t < 196) bpre[t] = x - v;
  if (t == 255) off[N_NODES] = x;
}

__global__ void scanC_k(const int* __restrict__ deg, int* __restrict__ off,
                        const int* __restrict__ bpre, int* __restrict__ cur){
  int i = blockIdx.x*256 + threadIdx.x;
  if (i >= N_NODES) return;
  int excl = off[i] - deg[i] + bpre[blockIdx.x];
  off[i] = excl; cur[i] = excl;
}

__global__ void scatter_k(const int* __restrict__ dst, int* __restrict__ cur, int* __restrict__ eid){
  int e = blockIdx.x*256 + threadIdx.x;
  if (e >= N_EDGES) return;
  int p = atomicAdd(&cur[dst[e]], 1);
  eid[p] = e;
}

// ---------------- pa/pb precompute ----------------
__global__ __launch_bounds__(512, 4) void pab_k(const u16* __restrict__ nfc,
                                                const char* __restrict__ wsw,
                                                u16* __restrict__ pa, u16* __restrict__ pb)
{
  const int t = threadIdx.x, lane = t & 63, wid = t >> 6;
  const int mw = wid & 1, nw = wid >> 1;
  const int mbase = mw << 5, nbase = nw << 6;
  const int l15 = lane & 15, l4 = lane >> 4;
  const int tile = blockIdx.x;
  const u16* Wt = (const u16*)(wsw + WS_WT_E1);
  const float* b1 = (const float*)(wsw + WS_B_E1);

  for (int sel = 0; sel < 2; ++sel){
    u16* out = sel ? pb : pa;
    f32x4 acc[2][4];
    #pragma unroll
    for (int mi=0;mi<2;mi++)
    #pragma unroll
    for (int ni=0;ni<4;ni++){ float b_ = sel ? 0.f : b1[nbase+ni*16+l15]; acc[mi][ni]=(f32x4){b_,b_,b_,b_}; }

    #pragma unroll
    for (int kk=0;kk<4;kk++){
      const int kel = kk*32 + l4*8;
      bf16x8 av[2];
      #pragma unroll
      for (int mi=0;mi<2;mi++){
        int row = tile*64 + mbase + mi*16 + l15;
        if (row >= N_NODES) row = 0;
        av[mi] = *(const bf16x8*)(nfc + (size_t)row*128 + kel);
      }
      #pragma unroll
      for (int ni=0;ni<4;ni++){
        int n_ = nbase + ni*16 + l15;
        bf16x8 bv = *(const bf16x8*)(Wt + (size_t)n_*256 + sel*128 + kel);
        #pragma unroll
        for (int mi=0;mi<2;mi++)
          acc[mi][ni] = __builtin_amdgcn_mfma_f32_16x16x32_bf16(av[mi], bv, acc[mi][ni], 0,0,0);
      }
    }
    #pragma unroll
    for (int mi=0;mi<2;mi++)
    #pragma unroll
    for (int ni=0;ni<4;ni++)
    #pragma unroll
    for (int j=0;j<4;j++){
      int m_ = tile*64 + mbase + mi*16 + l4*4 + j;
      if (m_ < N_NODES){
        int n_ = nbase + ni*16 + l15;
        out[(size_t)m_*256 + n_] = f2b(acc[mi][ni][j]);
      }
    }
  }
}

// ---------------- fused edge MLP ----------------
// 128-edge tiles (6250 blocks via XCD swizzle), 8 waves (2M x 4N); per-wave 64 rows x 64
// cols, acc[4][4] = 64 AGPR. Lean FRAG GEMM (no prefetch) keeps arch regs ~60 ->
// total ~124 <= 128 bucket: 2 blocks/CU, 16 waves, no spill (WRITE_SIZE is the tripwire).
#define FRAG_GEMM4(FB, BIAS_L) do { \
  _Pragma("unroll") for (int mi=0;mi<4;mi++) _Pragma("unroll") for (int ni=0;ni<4;ni++){ \
    float b_ = BIAS_L[nbase + ni*16 + l15]; acc[mi][ni] = (f32x4){b_,b_,b_,b_}; } \
  _Pragma("unroll") for (int kk=0;kk<8;kk++){ \
    const int kel = kk*32 + l4*8; \
    bf16x8 av[4]; \
    _Pragma("unroll") for (int mi=0;mi<4;mi++){ \
      int row = mbase + mi*16 + l15; \
      uint32_t byte = ((uint32_t)row<<9) ^ ((uint32_t)kel<<1) ^ ((uint32_t)(row&7)<<4); \
      av[mi] = *(const bf16x8*)((const char*)h_lds + byte); \
    } \
    _Pragma("unroll") for (int ni=0;ni<4;ni++){ \
      bf16x8 bv = *(const bf16x8*)(FB + (((kk<<4) + nblk0 + ni)<<9) + lane*8); \
      _Pragma("unroll") for (int mi=0;mi<4;mi++) \
        acc[mi][ni] = __builtin_amdgcn_mfma_f32_16x16x32_bf16(av[mi], bv, acc[mi][ni], 0,0,0); \
    } \
  } } while(0)

#define SILU_STORE4() do { \
  _Pragma("unroll") for (int mi=0;mi<4;mi++) _Pragma("unroll") for (int ni=0;ni<4;ni++) \
  _Pragma("unroll") for (int j=0;j<4;j++){ \
    int m_ = mbase + mi*16 + l4*4 + j; int n_ = nbase + ni*16 + l15; \
    float v_ = silu_f(acc[mi][ni][j]); \
    uint32_t byte = ((uint32_t)m_<<9) ^ ((uint32_t)n_<<1) ^ ((uint32_t)(m_&7)<<4); \
    *(u16*)((char*)h_lds + byte) = f2b(v_); \
  } } while(0)

template<bool PRE>
__global__ __launch_bounds__(512, 4) void edge_mlp(
    const u16* __restrict__ nfc, const float* __restrict__ coord,
    const int* __restrict__ src, const int* __restrict__ dst,
    const char* __restrict__ wsw, const int* __restrict__ eid,
    const u16* __restrict__ pa, const u16* __restrict__ pb,
    float* __restrict__ h_neigh, float* __restrict__ xsum)
{
  __shared__ u16 h_lds[32768];           // 64KB: [128 rows][256] bf16, XOR-swizzled
  __shared__ int s_ids[128], d_ids[128];
  __shared__ float rad_l[128], xd_l[128][3];
  __shared__ float cpart[4][128];
  __shared__ float b1_l[256], b2_l[256], b3_l[256], wc2_l[256];

  const int t = threadIdx.x, lane = t & 63, wid = t >> 6;   // 8 waves
  const int mw = wid & 1, nw = wid >> 1;
  const int mbase = mw << 6, nbase = nw << 6;
  const int nblk0 = nw << 2;
  const int l15 = lane & 15, l4 = lane >> 4;

  // bijective XCD-chunked swizzle: nwg=6250, q=781, r=2
  const int orig = blockIdx.x;
  const int xcd = orig & 7;
  const int tile = (xcd < 2 ? xcd*782 : 2*782 + (xcd-2)*781) + (orig >> 3);

  const u16* FB2 = (const u16*)(wsw + WS_WT_E2);
  const u16* FB3 = (const u16*)(wsw + WS_WT_C1);

  // ---- prologue: edge metadata + bias tables ----
  if (t < 128) {
    int e = eid[tile*128 + t];
    int s = src[e], d = dst[e];
    s_ids[t] = s; d_ids[t] = d;
    float ax = coord[s*3+0]-coord[d*3+0];
    float ay = coord[s*3+1]-coord[d*3+1];
    float az = coord[s*3+2]-coord[d*3+2];
    float r2 = ax*ax+ay*ay+az*az;
    float inv = 1.0f/(sqrtf(r2) + 1e-30f);
    rad_l[t] = r2; xd_l[t][0]=ax*inv; xd_l[t][1]=ay*inv; xd_l[t][2]=az*inv;
  }
  if (t >= 128 && t < 384) {
    int c = t - 128;
    if constexpr (!PRE) b1_l[c] = ((const float*)(wsw+WS_B_E1))[c];
    b2_l[c]  = ((const float*)(wsw+WS_B_E2))[c];
    b3_l[c]  = ((const float*)(wsw+WS_B_C1))[c];
    wc2_l[c] = ((const float*)(wsw+WS_WC2))[c];
  }
  __syncthreads();

  f32x4 acc[4][4];

  // ---- layer 1 ----
  if constexpr (PRE) {
    // h1[r][c] = silu(pa[s][c] + pb[d][c] + r*wr[c]); thread: row r1=t>>2, 64 cols
    const int r1 = t >> 2, cq = (t & 3) << 6;
    const int s1 = s_ids[r1], d1 = d_ids[r1];
    const float rr = rad_l[r1];
    const u16* par = pa + (size_t)s1*256 + cq;
    const u16* pbr = pb + (size_t)d1*256 + cq;
    const float* wrg = (const float*)(wsw + WS_WRAD) + cq;
    #pragma unroll
    for (int q=0;q<8;q++){
      u16x8 ua = *(const u16x8*)(par + q*8);
      u16x8 ub = *(const u16x8*)(pbr + q*8);
      f32x4 w0 = *(const f32x4*)(wrg + q*8);
      f32x4 w1 = *(const f32x4*)(wrg + q*8 + 4);
      u16x8 o;
      #pragma unroll
      for (int j=0;j<8;j++){
        float wv = (j<4) ? w0[j] : w1[j-4];
        float hv = silu_f(b2f(ua[j]) + b2f(ub[j]) + rr*wv);
        o[j] = f2b(hv);
      }
      int c = cq + q*8;
      uint32_t byte = ((uint32_t)r1<<9) ^ ((uint32_t)c<<1) ^ ((uint32_t)(r1&7)<<4);
      *(u16x8*)((char*)h_lds + byte) = o;
    }
  } else {
    #pragma unroll
    for (int mi=0;mi<4;mi++)
    #pragma unroll
    for (int ni=0;ni<4;ni++){ float b_ = b1_l[nbase+ni*16+l15]; acc[mi][ni]=(f32x4){b_,b_,b_,b_}; }
    const u16* Wt1 = (const u16*)(wsw + WS_WT_E1);
    #pragma unroll
    for (int kk=0;kk<8;kk++){
      const int kel = kk*32 + l4*8;
      bf16x8 av[4];
      #pragma unroll
      for (int mi=0;mi<4;mi++){
        int row = mbase + mi*16 + l15;
        int nid = (kk < 4) ? s_ids[row] : d_ids[row];
        int k = (kk < 4) ? kel : (kel - 128);
        av[mi] = *(const bf16x8*)(nfc + (size_t)nid*128 + k);
      }
      #pragma unroll
      for (int ni=0;ni<4;ni++){
        int n_ = nbase + ni*16 + l15;
        bf16x8 bv = *(const bf16x8*)(Wt1 + (size_t)n_*256 + kel);
        #pragma unroll
        for (int mi=0;mi<4;mi++)
          acc[mi][ni] = __builtin_amdgcn_mfma_f32_16x16x32_bf16(av[mi], bv, acc[mi][ni], 0,0,0);
      }
    }
    #pragma unroll
    for (int mi=0;mi<4;mi++)
    #pragma unroll
    for (int ni=0;ni<4;ni++){
      int n_ = nbase + ni*16 + l15;
      float wrn = ((const float*)(wsw+WS_WRAD))[n_];
      #pragma unroll
      for (int j=0;j<4;j++){
        int m_ = mbase + mi*16 + l4*4 + j;
        float v_ = silu_f(acc[mi][ni][j] + rad_l[m_]*wrn);
        uint32_t byte = ((uint32_t)m_<<9) ^ ((uint32_t)n_<<1) ^ ((uint32_t)(m_&7)<<4);
        *(u16*)((char*)h_lds + byte) = f2b(v_);
      }
    }
  }
  __syncthreads();

  // ---- layer 2: msg_h = silu(h1 @ W_e2 + b) ----
  FRAG_GEMM4(FB2, b2_l);
  __syncthreads();
  SILU_STORE4();
  __syncthreads();

  // ---- layer 3: c = (silu(msg_h @ W_c1 + b)) . w_c2 ----
  FRAG_GEMM4(FB3, b3_l);
  float part[4][4];
  #pragma unroll
  for (int mi=0;mi<4;mi++)
  #pragma unroll
  for (int j=0;j<4;j++) part[mi][j] = 0.f;
  #pragma unroll
  for (int mi=0;mi<4;mi++)
  #pragma unroll
  for (int ni=0;ni<4;ni++){
    int n_ = nbase + ni*16 + l15;
    float w = wc2_l[n_];
    #pragma unroll
    for (int j=0;j<4;j++) part[mi][j] += silu_f(acc[mi][ni][j]) * w;
  }
  #pragma unroll
  for (int off_=1; off_<16; off_<<=1)
  #pragma unroll
  for (int mi=0;mi<4;mi++)
  #pragma unroll
  for (int j=0;j<4;j++) part[mi][j] += __shfl_xor(part[mi][j], off_, 64);
  if (l15 == 0){
    #pragma unroll
    for (int mi=0;mi<4;mi++)
    #pragma unroll
    for (int j=0;j<4;j++){
      int m_ = mbase + mi*16 + l4*4 + j;
      cpart[nw][m_] = part[mi][j];
    }
  }
  __syncthreads();

  // ---- epilogue A: x-message, wave-segmented scan + 1 atomic per run ----
  if (t < 128){
    float csum = cpart[0][t] + cpart[1][t] + cpart[2][t] + cpart[3][t];
    int dd = d_ids[t];
    float v0 = csum*xd_l[t][0], v1 = csum*xd_l[t][1], v2 = csum*xd_l[t][2];
    #pragma unroll
    for (int off_=1; off_<64; off_<<=1){
      float u0=__shfl_up(v0,off_,64), u1=__shfl_up(v1,off_,64), u2=__shfl_up(v2,off_,64);
      int du=__shfl_up(dd,off_,64);
      if (lane >= off_ && du == dd){ v0+=u0; v1+=u1; v2+=u2; }
    }
    int dn = __shfl_down(dd,1,64);
    if (lane == 63 || dn != dd){
      unsafeAtomicAdd(&xsum[dd*3+0], v0);
      unsafeAtomicAdd(&xsum[dd*3+1], v1);
      unsafeAtomicAdd(&xsum[dd*3+2], v2);
    }
  }
  // ---- epilogue B: segmented reduce msg_h (2 halves x 64 rows x 256 cols), batched reads ----
  {
    int col  = t & 255;
    int half = t >> 8;                   // 0..1
    int rb   = half << 6;                // 64 rows per half
    float a2 = 0.f; int prev = d_ids[rb]; bool firstrun = true;
    #pragma unroll
    for (int ii=0; ii<64; ii+=8){
      float v[8]; int dv[8];
      #pragma unroll
      for (int j=0;j<8;j++){
        int m_ = rb + ii + j;
        uint32_t byte = ((uint32_t)m_<<9) ^ ((uint32_t)col<<1) ^ ((uint32_t)(m_&7)<<4);
        v[j] = b2f(*(const u16*)((const char*)h_lds + byte));
        dv[j] = d_ids[m_];
      }
      #pragma unroll
      for (int j=0;j<8;j++){
        if (dv[j] != prev){
          float* p = &h_neigh[(size_t)prev*256 + col];
          if (firstrun) unsafeAtomicAdd(p, a2); else *p = a2;
          firstrun = false; a2 = v[j]; prev = dv[j];
        } else a2 += v[j];
      }
    }
    unsafeAtomicAdd(&h_neigh[(size_t)prev*256 + col], a2);
  }
}

// ---------------- node MLP ----------------
#define SILU_STORE2N() do { \
  _Pragma("unroll") for (int mi=0;mi<2;mi++) _Pragma("unroll") for (int ni=0;ni<4;ni++) \
  _Pragma("unroll") for (int j=0;j<4;j++){ \
    int m_ = mbase + mi*16 + l4*4 + j; int n_ = nbase + ni*16 + l15; \
    float v_ = silu_f(acc[mi][ni][j]); \
    uint32_t byte = ((uint32_t)m_<<9) ^ ((uint32_t)n_<<1) ^ ((uint32_t)(m_&7)<<4); \
    *(u16*)((char*)h_lds + byte) = f2b(v_); \
  } } while(0)

__global__ __launch_bounds__(512, 4) void node_mlp(
    const u16* __restrict__ node_feat, const float* __restrict__ h_neigh,
    const char* __restrict__ wsw, u16* __restrict__ hpre)
{
  __shared__ u16 h_lds[16384];           // 32KB: [64 rows][256] bf16, XOR-swizzled
  __shared__ float b1_l[256], b2_l[128];

  const int t = threadIdx.x, lane = t & 63, wid = t >> 6;
  const int mw = wid & 1, nw = wid >> 1;
  const int mbase = mw << 5, nbase = nw << 6;
  const int l15 = lane & 15, l4 = lane >> 4;
  const int tile = blockIdx.x;

  if (t < 256) b1_l[t] = ((const float*)(wsw+WS_B_N1))[t];
  if (t < 128) b2_l[t] = ((const float*)(wsw+WS_B_N2))[t];
  __syncthreads();

  const u16* Wt1 = (const u16*)(wsw + WS_WT_N1);   // [256][384]
  const u16* Wt2 = (const u16*)(wsw + WS_WT_N2);   // [128][256]

  f32x4 acc[2][4];
  #pragma unroll
  for (int mi=0;mi<2;mi++)
  #pragma unroll
  for (int ni=0;ni<4;ni++){ float b_ = b1_l[nbase+ni*16+l15]; acc[mi][ni] = (f32x4){b_,b_,b_,b_}; }

  #pragma unroll
  for (int kk=0;kk<12;kk++){
    const int kel = kk*32 + l4*8;
    bf16x8 av[2];
    #pragma unroll
    for (int mi=0;mi<2;mi++){
      int row = tile*64 + mbase + mi*16 + l15;
      if (row >= N_NODES) row = 0;
      if (kk < 4){
        av[mi] = *(const bf16x8*)(node_feat + (size_t)row*128 + kel);
      } else {
        const float* hp = h_neigh + (size_t)row*256 + (kel - 128);
        f32x4 h0 = *(const f32x4*)(hp);
        f32x4 h1 = *(const f32x4*)(hp + 4);
        u16x8 u;
        #pragma unroll
        for (int e2=0;e2<4;e2++){ u[e2] = f2b(h0[e2]); u[e2+4] = f2b(h1[e2]); }
        av[mi] = __builtin_bit_cast(bf16x8, u);
      }
    }
    #pragma unroll
    for (int ni=0;ni<4;ni++){
      int n_ = nbase + ni*16 + l15;
      bf16x8 bv = *(const bf16x8*)(Wt1 + (size_t)n_*384 + kel);
      #pragma unroll
      for (int mi=0;mi<2;mi++)
        acc[mi][ni] = __builtin_amdgcn_mfma_f32_16x16x32_bf16(av[mi], bv, acc[mi][ni], 0,0,0);
    }
  }
  SILU_STORE2N();
  __syncthreads();

  const int nb2 = nw << 5;
  f32x4 acc2[2][2];
  #pragma unroll
  for (int mi=0;mi<2;mi++)
  #pragma unroll
  for (int ni=0;ni<2;ni++){ float b_ = b2_l[nb2+ni*16+l15]; acc2[mi][ni] = (f32x4){b_,b_,b_,b_}; }
  #pragma unroll
  for (int kk=0;kk<8;kk++){
    const int kel = kk*32 + l4*8;
    bf16x8 av[2];
    #pragma unroll
    for (int mi=0;mi<2;mi++){
      int row = mbase + mi*16 + l15;
      uint32_t byte = ((uint32_t)row<<9) ^ ((uint32_t)kel<<1) ^ ((uint32_t)(row&7)<<4);
      av[mi] = *(const bf16x8*)((const char*)h_lds + byte);
    }
    #pragma unroll
    for (int ni=0;ni<2;ni++){
      int n_ = nb2 + ni*16 + l15;
      bf16x8 bv = *(const bf16x8*)(Wt2 + (size_t)n_*256 + kel);
      #pragma unroll
      for (int mi=0;mi<2;mi++)
        acc2[mi][ni] = __builtin_amdgcn_mfma_f32_16x16x32_bf16(av[mi], bv, acc2[mi][ni], 0,0,0);
    }
  }
  #pragma unroll
  for (int mi=0;mi<2;mi++)
  #pragma unroll
  for (int ni=0;ni<2;ni++)
  #pragma unroll
  for (int j=0;j<4;j++){
    int m_ = tile*64 + mbase + mi*16 + l4*4 + j;
    if (m_ < N_NODES){
      int n_ = nb2 + ni*16 + l15;
      hpre[(size_t)m_*128 + n_] = f2b(acc2[mi][ni][j]);
    }
  }
}

// ---------------- BatchNorm stats/final ----------------
__global__ void bn_stats_k(const u16* __restrict__ hpre, float* __restrict__ stat){
  int c = threadIdx.x;
  float s = 0.f, s2 = 0.f;
  for (int r = blockIdx.x; r < N_NODES; r += 256){
    float v = b2f(hpre[(size_t)r*128 + c]);
    s += v; s2 += v*v;
  }
  atomicAdd(&stat[c], s);
  atomicAdd(&stat[128+c], s2);
}

__global__ void bn_final_k(const float* __restrict__ stat, const char* __restrict__ wsw,
                           float* __restrict__ scale, float* __restrict__ shift){
  int c = threadIdx.x;
  if (c >= 128) return;
  float mu = stat[c] * (1.0f/N_NODES);
  float var = stat[128+c] * (1.0f/N_NODES) - mu*mu;
  float rs = rsqrtf(var + 1e-5f);
  float g = ((const float*)(wsw+WS_GAMMA))[c];
  float b = ((const float*)(wsw+WS_BETA))[c];
  scale[c] = rs*g;
  shift[c] = b - mu*rs*g;
}

// ---------------- fused finish: bn_apply | x_out ----------------
__global__ void finish_k(const u16* __restrict__ hpre, const float* __restrict__ scale,
                         const float* __restrict__ shift, const float* __restrict__ coord,
                         const int* __restrict__ deg, const float* __restrict__ xsum,
                         void* __restrict__ d_out, const int* __restrict__ flagp)
{
  const int b = blockIdx.x;
  const int fl = *flagp;
  if (b < 3125){
    int i = b*256 + threadIdx.x;
    if (i >= N_NODES*128/8) return;
    u16x8 v = *(const u16x8*)(hpre + (size_t)i*8);
    int c0 = (i*8) & 127;
    if (fl){
      float* o = (float*)d_out + (size_t)i*8;
      #pragma unroll
      for (int j=0;j<8;j++) o[j] = b2f(v[j])*scale[c0+j] + shift[c0+j];
    } else {
      u16x8 w;
      #pragma unroll
      for (int j=0;j<8;j++) w[j] = f2b(b2f(v[j])*scale[c0+j] + shift[c0+j]);
      *(u16x8*)((u16*)d_out + (size_t)i*8) = w;
    }
    return;
  }
  {
    int n = (b-3125)*256 + threadIdx.x;
    if (n >= N_NODES) return;
    float dm = fmaxf((float)deg[n], 1.f);
    float v0 = coord[n*3+0] + xsum[n*3+0]/dm;
    float v1 = coord[n*3+1] + xsum[n*3+1]/dm;
    float v2 = coord[n*3+2] + xsum[n*3+2]/dm;
    const size_t base = (size_t)N_NODES*128 + (size_t)n*3;
    if (fl){
      float* o = (float*)d_out;
      o[base+0]=v0; o[base+1]=v1; o[base+2]=v2;
    } else {
      u16* o = (u16*)d_out;
      o[base+0]=f2b(v0); o[base+1]=f2b(v1); o[base+2]=f2b(v2);
    }
  }
}

// ---------------- launch ----------------
extern "C" void kernel_launch(void* const* d_in, const int* in_sizes, int n_in,
                              void* d_out, int out_size, void* d_ws, size_t ws_size,
                              hipStream_t stream)
{
  const void* node_feat_raw = d_in[0];
  const void* coord_raw     = d_in[1];
  const int* src       = (const int*)d_in[2];
  const int* dst       = (const int*)d_in[3];
  char* ws = (char*)d_ws;

  int*   flag  = (int*)(ws + WS_FLAG);
  int*   deg   = (int*)(ws + WS_DEG);
  int*   off   = (int*)(ws + WS_OFF);
  int*   bsum  = (int*)(ws + WS_BSUM);
  int*   bpre  = (int*)(ws + WS_BPRE);
  int*   cur   = (int*)(ws + WS_CUR);
  int*   eid   = (int*)(ws + WS_EID);
  float* xsum  = (float*)(ws + WS_XSUM);
  float* hn    = (float*)(ws + WS_HN);
  u16*   pa    = (u16*)(ws + WS_PA);
  u16*   pb    = (u16*)(ws + WS_PB);
  u16*   hpre  = (u16*)(ws + WS_PA);   // aliases pa (dead after edge phase)
  const u16*   nfc = (const u16*)(ws + WS_NF);
  const float* cfc = (const float*)(ws + WS_CF);
  float* stat  = (float*)(ws + WS_STAT);
  float* scale = (float*)(ws + WS_SCALE);
  float* shift = (float*)(ws + WS_SHIFT);

  const bool pre = (ws_size >= (size_t)WS_PRE_END);

  hipMemsetAsync(deg, 0, N_NODES*sizeof(int), stream);
  hipMemsetAsync(xsum, 0, N_NODES*3*sizeof(float), stream);
  hipMemsetAsync(hn, 0, (size_t)N_NODES*256*sizeof(float), stream);
  hipMemsetAsync(stat, 0, 256*sizeof(float), stream);

  detect_k<<<1,64,0,stream>>>(node_feat_raw, flag);
  prep_all_k<<<11250,256,0,stream>>>(node_feat_raw, coord_raw,
                                     d_in[4],d_in[5],d_in[6],d_in[7],d_in[8],d_in[9],
                                     d_in[10],d_in[11],d_in[12],d_in[13],d_in[14],
                                     d_in[15],d_in[16], dst, deg, ws, flag);
  scanA_k<<<196,256,0,stream>>>(deg, off, bsum);
  scanB_k<<<1,256,0,stream>>>(bsum, bpre, off);
  scanC_k<<<196,256,0,stream>>>(deg, off, bpre, cur);
  scatter_k<<<3125,256,0,stream>>>(dst, cur, eid);

  if (pre){
    pab_k<<<782,512,0,stream>>>(nfc, ws, pa, pb);
    edge_mlp<true><<<6250,512,0,stream>>>(nfc, cfc, src, dst, ws, eid, pa, pb, hn, xsum);
  } else {
    edge_mlp<false><<<6250,512,0,stream>>>(nfc, cfc, src, dst, ws, eid, pa, pb, hn, xsum);
  }

  node_mlp<<<782,512,0,stream>>>(nfc, hn, ws, hpre);
  bn_stats_k<<<256,128,0,stream>>>(hpre, stat);
  bn_final_k<<<1,128,0,stream>>>(stat, ws, scale, shift);
  finish_k<<<3321,256,0,stream>>>(hpre, scale, shift, cfc, deg, xsum, d_out, flag);
}

// Round 14
// 805.257 us; speedup vs baseline: 1.1994x; 1.1994x over previous
//
#include <hip/hip_runtime.h>
#include <stdint.h>

typedef unsigned short u16;
typedef __bf16 bf16x8 __attribute__((ext_vector_type(8)));
typedef unsigned short u16x8 __attribute__((ext_vector_type(8)));
typedef float f32x4 __attribute__((ext_vector_type(4)));

#define N_NODES 50000
#define N_EDGES 800000

enum : uint32_t {
  WS_WT_E1 = 0u,          // [256][256] bf16 plain W_e1^T (k<128 src part, k>=128 dst part)
  WS_WT_E2 = 131072u,     // FRAG layout [8][16][64][8] bf16 (W_e2 B-fragments)
  WS_WT_C1 = 262144u,     // FRAG layout (W_c1)
  WS_WT_N1 = 393216u,     // [256][384] bf16 plain
  WS_WT_N2 = 589824u,     // [128][256] bf16 plain
  WS_WRAD  = 655360u,     // f32[256]
  WS_WC2   = 656384u,     // f32[256]
  WS_B_E1  = 657408u,
  WS_B_E2  = 658432u,
  WS_B_C1  = 659456u,
  WS_B_N1  = 660480u,
  WS_B_N2  = 661504u,
  WS_GAMMA = 662016u,
  WS_BETA  = 662528u,
  WS_SCALE = 663040u,
  WS_SHIFT = 663552u,
  WS_STAT  = 664064u,
  WS_FLAG  = 665600u,
  WS_DEG   = 1048576u,    // int[50000]
  WS_OFF   = 1248576u,    // int[50001]
  WS_BSUM  = 1448704u,
  WS_BPRE  = 1449728u,
  WS_CUR   = 1450752u,    // int[50000]
  WS_EID   = 1650752u,    // int[800000]         ends 4850752
  WS_XSUM  = 4850752u,    // f32[50000*3]
  WS_CF    = 5450752u,    // f32[50000*3]
  WS_NF    = 6050752u,    // bf16[50000*128]     ends 18850752
  WS_HN    = 18850752u,   // f32[50000*256]      ends 70050752
  WS_PA    = 70050752u,   // bf16[50048*256] (PRE) / hpre alias
  WS_PB    = 95675328u,   // bf16[50048*256] (PRE only)
  WS_PRE_END = 121299904u
};

__device__ __forceinline__ float b2f(u16 u){ uint32_t x=((uint32_t)u)<<16; float f; __builtin_memcpy(&f,&x,4); return f; }
__device__ __forceinline__ u16 f2b(float f){ __bf16 h = (__bf16)f; return __builtin_bit_cast(unsigned short, h); }
__device__ __forceinline__ float silu_f(float x){
  return x * __builtin_amdgcn_rcpf(1.0f + __expf(-x));
}
__device__ __forceinline__ float ldin(const void* p, int i, int fl){
  return fl ? ((const float*)p)[i] : b2f(((const u16*)p)[i]);
}

// ---------------- dtype detect ----------------
__global__ void detect_k(const void* nf, int* flag){
  if (threadIdx.x == 0){
    const u16* p = (const u16*)nf;
    int cnt = 0;
    for (int i=0;i<128;i++){
      u16 u = p[2*i];
      int e = (u >> 7) & 0xFF;
      if (e >= 0x90) cnt++;
    }
    *flag = (cnt >= 8) ? 1 : 0;
  }
}

// ---------------- fused prep: cvt_nf | cvt_cf | weight prep | histo ----------------
// block ranges: [0,6250) cvt_nf, [6250,6837) cvt_cf, [6837,8125) prep, [8125,11250) histo
__global__ void prep_all_k(const void* nf, const void* cd,
                           const void* We1, const void* be1, const void* We2, const void* be2,
                           const void* Wc1, const void* bc1, const void* Wc2,
                           const void* Wn1, const void* bn1, const void* Wn2, const void* bn2,
                           const void* gam, const void* bet,
                           const int* __restrict__ dst, int* __restrict__ deg,
                           char* ws, const int* flagp)
{
  const int b = blockIdx.x;
  const int fl = *flagp;
  if (b < 6250){
    int i = b*256 + threadIdx.x;
    if (i >= (N_NODES*128)/4) return;
    ushort4* out = (ushort4*)(ws + WS_NF);
    if (fl){
      const float4* p = (const float4*)nf;
      float4 v = p[i];
      ushort4 o; o.x=f2b(v.x); o.y=f2b(v.y); o.z=f2b(v.z); o.w=f2b(v.w);
      out[i] = o;
    } else {
      out[i] = ((const ushort4*)nf)[i];
    }
    return;
  }
  if (b < 6837){
    int i = (b-6250)*256 + threadIdx.x;
    if (i >= N_NODES*3) return;
    ((float*)(ws + WS_CF))[i] = ldin(cd, i, fl);
    return;
  }
  if (b < 8125){
    int g = (b-6837)*256 + threadIdx.x;
    if (g < 65536){ int n=g>>8,k=g&255; ((u16*)(ws+WS_WT_E1))[n*256+k]=f2b(ldin(We1,k*256+n,fl)); return; } g-=65536;
    if (g < 65536){
      int j=g&7, l=(g>>3)&63, nblk=(g>>9)&15, kk=g>>13;
      int n=nblk*16+(l&15), k=kk*32+((l>>4)&3)*8+j;
      ((u16*)(ws+WS_WT_E2))[g]=f2b(ldin(We2,k*256+n,fl)); return; } g-=65536;
    if (g < 65536){
      int j=g&7, l=(g>>3)&63, nblk=(g>>9)&15, kk=g>>13;
      int n=nblk*16+(l&15), k=kk*32+((l>>4)&3)*8+j;
      ((u16*)(ws+WS_WT_C1))[g]=f2b(ldin(Wc1,k*256+n,fl)); return; } g-=65536;
    if (g < 98304){ int n=g/384,k=g-n*384; ((u16*)(ws+WS_WT_N1))[n*384+k]=f2b(ldin(Wn1,k*256+n,fl)); return; } g-=98304;
    if (g < 32768){ int n=g>>8,k=g&255; ((u16*)(ws+WS_WT_N2))[n*256+k]=f2b(ldin(Wn2,k*128+n,fl)); return; } g-=32768;
    if (g < 256){ ((float*)(ws+WS_WRAD))[g]=ldin(We1,65536+g,fl); return; } g-=256;
    if (g < 256){ ((float*)(ws+WS_WC2))[g]=ldin(Wc2,g,fl); return; } g-=256;
    if (g < 256){ ((float*)(ws+WS_B_E1))[g]=ldin(be1,g,fl); return; } g-=256;
    if (g < 256){ ((float*)(ws+WS_B_E2))[g]=ldin(be2,g,fl); return; } g-=256;
    if (g < 256){ ((float*)(ws+WS_B_C1))[g]=ldin(bc1,g,fl); return; } g-=256;
    if (g < 256){ ((float*)(ws+WS_B_N1))[g]=ldin(bn1,g,fl); return; } g-=256;
    if (g < 128){ ((float*)(ws+WS_B_N2))[g]=ldin(bn2,g,fl); return; } g-=128;
    if (g < 128){ ((float*)(ws+WS_GAMMA))[g]=ldin(gam,g,fl); return; } g-=128;
    if (g < 128){ ((float*)(ws+WS_BETA))[g]=ldin(bet,g,fl); return; }
    return;
  }
  {
    int e = (b-8125)*256 + threadIdx.x;
    if (e < N_EDGES) atomicAdd(&deg[dst[e]], 1);
  }
}

// ---------------- CSR build ----------------
__global__ void scanA_k(const int* __restrict__ deg, int* __restrict__ off, int* __restrict__ bsum){
  int t = threadIdx.x; int i = blockIdx.x*256 + t;
  int lane = t & 63, w = t >> 6;
  int v = (i < N_NODES) ? deg[i] : 0;
  int x = v;
  #pragma unroll
  for (int d=1; d<64; d<<=1){ int o = __shfl_up(x, d, 64); if (lane >= d) x += o; }
  __shared__ int wt[4];
  if (lane == 63) wt[w] = x;
  __syncthreads();
  int add = 0;
  if (w > 0) add += wt[0];
  if (w > 1) add += wt[1];
  if (w > 2) add += wt[2];
  x += add;
  if (i < N_NODES) off[i] = x;
  if (t == 255) bsum[blockIdx.x] = x;
}

__global__ void scanB_k(const int* __restrict__ bsum, int* __restrict__ bpre, int* __restrict__ off){
  int t = threadIdx.x;
  int lane = t & 63, w = t >> 6;
  int v = (t < 196) ? bsum[t] : 0;
  int x = v;
  #pragma unroll
  for (int d=1; d<64; d<<=1){ int o = __shfl_up(x, d, 64); if (lane >= d) x += o; }
  __shared__ int wt[4];
  if (lane == 63) wt[w] = x;
  __syncthreads();
  int add = 0;
  if (w > 0) add += wt[0];
  if (w > 1) add += wt[1];
  if (w > 2) add += wt[2];
  x += add;
  if (t < 196) bpre[t] = x - v;
  if (t == 255) off[N_NODES] = x;
}

__global__ void scanC_k(const int* __restrict__ deg, int* __restrict__ off,
                        const int* __restrict__ bpre, int* __restrict__ cur){
  int i = blockIdx.x*256 + threadIdx.x;
  if (i >= N_NODES) return;
  int excl = off[i] - deg[i] + bpre[blockIdx.x];
  off[i] = excl; cur[i] = excl;
}

__global__ void scatter_k(const int* __restrict__ dst, int* __restrict__ cur, int* __restrict__ eid){
  int e = blockIdx.x*256 + threadIdx.x;
  if (e >= N_EDGES) return;
  int p = atomicAdd(&cur[dst[e]], 1);
  eid[p] = e;
}

// ---------------- pa/pb precompute ----------------
__global__ __launch_bounds__(512, 4) void pab_k(const u16* __restrict__ nfc,
                                                const char* __restrict__ wsw,
                                                u16* __restrict__ pa, u16* __restrict__ pb)
{
  const int t = threadIdx.x, lane = t & 63, wid = t >> 6;
  const int mw = wid & 1, nw = wid >> 1;
  const int mbase = mw << 5, nbase = nw << 6;
  const int l15 = lane & 15, l4 = lane >> 4;
  const int tile = blockIdx.x;
  const u16* Wt = (const u16*)(wsw + WS_WT_E1);
  const float* b1 = (const float*)(wsw + WS_B_E1);

  for (int sel = 0; sel < 2; ++sel){
    u16* out = sel ? pb : pa;
    f32x4 acc[2][4];
    #pragma unroll
    for (int mi=0;mi<2;mi++)
    #pragma unroll
    for (int ni=0;ni<4;ni++){ float b_ = sel ? 0.f : b1[nbase+ni*16+l15]; acc[mi][ni]=(f32x4){b_,b_,b_,b_}; }

    #pragma unroll
    for (int kk=0;kk<4;kk++){
      const int kel = kk*32 + l4*8;
      bf16x8 av[2];
      #pragma unroll
      for (int mi=0;mi<2;mi++){
        int row = tile*64 + mbase + mi*16 + l15;
        if (row >= N_NODES) row = 0;
        av[mi] = *(const bf16x8*)(nfc + (size_t)row*128 + kel);
      }
      #pragma unroll
      for (int ni=0;ni<4;ni++){
        int n_ = nbase + ni*16 + l15;
        bf16x8 bv = *(const bf16x8*)(Wt + (size_t)n_*256 + sel*128 + kel);
        #pragma unroll
        for (int mi=0;mi<2;mi++)
          acc[mi][ni] = __builtin_amdgcn_mfma_f32_16x16x32_bf16(av[mi], bv, acc[mi][ni], 0,0,0);
      }
    }
    #pragma unroll
    for (int mi=0;mi<2;mi++)
    #pragma unroll
    for (int ni=0;ni<4;ni++)
    #pragma unroll
    for (int j=0;j<4;j++){
      int m_ = tile*64 + mbase + mi*16 + l4*4 + j;
      if (m_ < N_NODES){
        int n_ = nbase + ni*16 + l15;
        out[(size_t)m_*256 + n_] = f2b(acc[mi][ni][j]);
      }
    }
  }
}

// ---------------- fused edge MLP ----------------
// 64-edge tiles (12500 blocks via bijective XCD-chunked swizzle), 8 waves (2M x 4N);
// per-wave 32 rows x 64 cols, acc[2][4]. FRAG weights + bv rolling prefetch.
// ~84-128 total regs -> 16 waves/CU, no spill (verified WRITE_SIZE ~76MB).
#define FRAG_GEMM2(FB, BIAS_L) do { \
  _Pragma("unroll") for (int mi=0;mi<2;mi++) _Pragma("unroll") for (int ni=0;ni<4;ni++){ \
    float b_ = BIAS_L[nbase + ni*16 + l15]; acc[mi][ni] = (f32x4){b_,b_,b_,b_}; } \
  bf16x8 bvc[4]; \
  _Pragma("unroll") for (int ni=0;ni<4;ni++) \
    bvc[ni] = *(const bf16x8*)(FB + (((nblk0 + ni)<<9)) + lane*8); \
  _Pragma("unroll") for (int kk=0;kk<8;kk++){ \
    const int kel = kk*32 + l4*8; \
    bf16x8 av[2]; \
    _Pragma("unroll") for (int mi=0;mi<2;mi++){ \
      int row = mbase + mi*16 + l15; \
      uint32_t byte = ((uint32_t)row<<9) ^ ((uint32_t)kel<<1) ^ ((uint32_t)(row&7)<<4); \
      av[mi] = *(const bf16x8*)((const char*)h_lds + byte); \
    } \
    bf16x8 bvn[4]; \
    if (kk < 7){ \
      _Pragma("unroll") for (int ni=0;ni<4;ni++) \
        bvn[ni] = *(const bf16x8*)(FB + ((((kk+1)<<4) + nblk0 + ni)<<9) + lane*8); \
    } \
    _Pragma("unroll") for (int ni=0;ni<4;ni++) \
    _Pragma("unroll") for (int mi=0;mi<2;mi++) \
      acc[mi][ni] = __builtin_amdgcn_mfma_f32_16x16x32_bf16(av[mi], bvc[ni], acc[mi][ni], 0,0,0); \
    if (kk < 7){ \
      _Pragma("unroll") for (int ni=0;ni<4;ni++) bvc[ni] = bvn[ni]; \
    } \
  } } while(0)

#define SILU_STORE2() do { \
  _Pragma("unroll") for (int mi=0;mi<2;mi++) _Pragma("unroll") for (int ni=0;ni<4;ni++) \
  _Pragma("unroll") for (int j=0;j<4;j++){ \
    int m_ = mbase + mi*16 + l4*4 + j; int n_ = nbase + ni*16 + l15; \
    float v_ = silu_f(acc[mi][ni][j]); \
    uint32_t byte = ((uint32_t)m_<<9) ^ ((uint32_t)n_<<1) ^ ((uint32_t)(m_&7)<<4); \
    *(u16*)((char*)h_lds + byte) = f2b(v_); \
  } } while(0)

template<bool PRE>
__global__ __launch_bounds__(512, 4) void edge_mlp(
    const u16* __restrict__ nfc, const float* __restrict__ coord,
    const int* __restrict__ src, const int* __restrict__ dst,
    const char* __restrict__ wsw, const int* __restrict__ eid,
    const u16* __restrict__ pa, const u16* __restrict__ pb,
    float* __restrict__ h_neigh, float* __restrict__ xsum)
{
  __shared__ u16 h_lds[16384];           // 32KB: [64 rows][256] bf16, XOR-swizzled
  __shared__ int s_ids[64], d_ids[64];
  __shared__ float rad_l[64], xd_l[64][3];
  __shared__ float cpart[4][64];
  __shared__ float b1_l[256], b2_l[256], b3_l[256], wc2_l[256];

  const int t = threadIdx.x, lane = t & 63, wid = t >> 6;   // 8 waves
  const int mw = wid & 1, nw = wid >> 1;
  const int mbase = mw << 5, nbase = nw << 6;
  const int nblk0 = nw << 2;
  const int l15 = lane & 15, l4 = lane >> 4;

  // bijective XCD-chunked swizzle: nwg=12500, q=1562, r=4
  const int orig = blockIdx.x;
  const int xcd = orig & 7;
  const int tile = (xcd < 4 ? xcd*1563 : 4*1563 + (xcd-4)*1562) + (orig >> 3);

  const u16* FB2 = (const u16*)(wsw + WS_WT_E2);
  const u16* FB3 = (const u16*)(wsw + WS_WT_C1);

  // ---- prologue: edge metadata + bias tables ----
  if (t < 64) {
    int e = eid[tile*64 + t];
    int s = src[e], d = dst[e];
    s_ids[t] = s; d_ids[t] = d;
    float ax = coord[s*3+0]-coord[d*3+0];
    float ay = coord[s*3+1]-coord[d*3+1];
    float az = coord[s*3+2]-coord[d*3+2];
    float r2 = ax*ax+ay*ay+az*az;
    float inv = 1.0f/(sqrtf(r2) + 1e-30f);
    rad_l[t] = r2; xd_l[t][0]=ax*inv; xd_l[t][1]=ay*inv; xd_l[t][2]=az*inv;
  }
  if (t >= 64 && t < 320) {
    int c = t - 64;
    if constexpr (!PRE) b1_l[c] = ((const float*)(wsw+WS_B_E1))[c];
    b2_l[c]  = ((const float*)(wsw+WS_B_E2))[c];
    b3_l[c]  = ((const float*)(wsw+WS_B_C1))[c];
    wc2_l[c] = ((const float*)(wsw+WS_WC2))[c];
  }
  __syncthreads();

  f32x4 acc[2][4];

  // ---- layer 1 ----
  if constexpr (PRE) {
    const int r1 = t >> 3, cq = (t & 7) << 5;
    const int s1 = s_ids[r1], d1 = d_ids[r1];
    const float rr = rad_l[r1];
    const u16* par = pa + (size_t)s1*256 + cq;
    const u16* pbr = pb + (size_t)d1*256 + cq;
    const float* wrg = (const float*)(wsw + WS_WRAD) + cq;
    u16x8 ua[4], ub[4];
    #pragma unroll
    for (int q=0;q<4;q++){ ua[q] = *(const u16x8*)(par + q*8); ub[q] = *(const u16x8*)(pbr + q*8); }
    #pragma unroll
    for (int q=0;q<4;q++){
      f32x4 w0 = *(const f32x4*)(wrg + q*8);
      f32x4 w1 = *(const f32x4*)(wrg + q*8 + 4);
      u16x8 o;
      #pragma unroll
      for (int j=0;j<8;j++){
        float wv = (j<4) ? w0[j] : w1[j-4];
        float hv = silu_f(b2f(ua[q][j]) + b2f(ub[q][j]) + rr*wv);
        o[j] = f2b(hv);
      }
      int c = cq + q*8;
      uint32_t byte = ((uint32_t)r1<<9) ^ ((uint32_t)c<<1) ^ ((uint32_t)(r1&7)<<4);
      *(u16x8*)((char*)h_lds + byte) = o;
    }
  } else {
    #pragma unroll
    for (int mi=0;mi<2;mi++)
    #pragma unroll
    for (int ni=0;ni<4;ni++){ float b_ = b1_l[nbase+ni*16+l15]; acc[mi][ni]=(f32x4){b_,b_,b_,b_}; }
    const u16* Wt1 = (const u16*)(wsw + WS_WT_E1);
    #pragma unroll
    for (int kk=0;kk<8;kk++){
      const int kel = kk*32 + l4*8;
      bf16x8 av[2];
      #pragma unroll
      for (int mi=0;mi<2;mi++){
        int row = mbase + mi*16 + l15;
        int nid = (kk < 4) ? s_ids[row] : d_ids[row];
        int k = (kk < 4) ? kel : (kel - 128);
        av[mi] = *(const bf16x8*)(nfc + (size_t)nid*128 + k);
      }
      #pragma unroll
      for (int ni=0;ni<4;ni++){
        int n_ = nbase + ni*16 + l15;
        bf16x8 bv = *(const bf16x8*)(Wt1 + (size_t)n_*256 + kel);
        #pragma unroll
        for (int mi=0;mi<2;mi++)
          acc[mi][ni] = __builtin_amdgcn_mfma_f32_16x16x32_bf16(av[mi], bv, acc[mi][ni], 0,0,0);
      }
    }
    #pragma unroll
    for (int mi=0;mi<2;mi++)
    #pragma unroll
    for (int ni=0;ni<4;ni++){
      int n_ = nbase + ni*16 + l15;
      float wrn = ((const float*)(wsw+WS_WRAD))[n_];
      #pragma unroll
      for (int j=0;j<4;j++){
        int m_ = mbase + mi*16 + l4*4 + j;
        float v_ = silu_f(acc[mi][ni][j] + rad_l[m_]*wrn);
        uint32_t byte = ((uint32_t)m_<<9) ^ ((uint32_t)n_<<1) ^ ((uint32_t)(m_&7)<<4);
        *(u16*)((char*)h_lds + byte) = f2b(v_);
      }
    }
  }
  __syncthreads();

  // ---- layer 2: msg_h = silu(h1 @ W_e2 + b) ----
  FRAG_GEMM2(FB2, b2_l);
  __syncthreads();
  SILU_STORE2();
  __syncthreads();

  // ---- layer 3: c = (silu(msg_h @ W_c1 + b)) . w_c2 ----
  FRAG_GEMM2(FB3, b3_l);
  float part[2][4];
  #pragma unroll
  for (int mi=0;mi<2;mi++)
  #pragma unroll
  for (int j=0;j<4;j++) part[mi][j] = 0.f;
  #pragma unroll
  for (int mi=0;mi<2;mi++)
  #pragma unroll
  for (int ni=0;ni<4;ni++){
    int n_ = nbase + ni*16 + l15;
    float w = wc2_l[n_];
    #pragma unroll
    for (int j=0;j<4;j++) part[mi][j] += silu_f(acc[mi][ni][j]) * w;
  }
  #pragma unroll
  for (int off_=1; off_<16; off_<<=1)
  #pragma unroll
  for (int mi=0;mi<2;mi++)
  #pragma unroll
  for (int j=0;j<4;j++) part[mi][j] += __shfl_xor(part[mi][j], off_, 64);
  if (l15 == 0){
    #pragma unroll
    for (int mi=0;mi<2;mi++)
    #pragma unroll
    for (int j=0;j<4;j++){
      int m_ = mbase + mi*16 + l4*4 + j;
      cpart[nw][m_] = part[mi][j];
    }
  }
  __syncthreads();

  // ---- epilogue A: x-message, wave-segmented scan + 1 atomic per run (wave 0) ----
  if (t < 64){
    float csum = cpart[0][t] + cpart[1][t] + cpart[2][t] + cpart[3][t];
    int dd = d_ids[t];
    float v0 = csum*xd_l[t][0], v1 = csum*xd_l[t][1], v2 = csum*xd_l[t][2];
    #pragma unroll
    for (int off_=1; off_<64; off_<<=1){
      float u0=__shfl_up(v0,off_,64), u1=__shfl_up(v1,off_,64), u2=__shfl_up(v2,off_,64);
      int du=__shfl_up(dd,off_,64);
      if (lane >= off_ && du == dd){ v0+=u0; v1+=u1; v2+=u2; }
    }
    int dn = __shfl_down(dd,1,64);
    if (lane == 63 || dn != dd){
      unsafeAtomicAdd(&xsum[dd*3+0], v0);
      unsafeAtomicAdd(&xsum[dd*3+1], v1);
      unsafeAtomicAdd(&xsum[dd*3+2], v2);
    }
  }
  // ---- epilogue B: segmented reduce msg_h (2 halves x 32 rows x 256 cols), batched reads ----
  {
    int col  = t & 255;
    int half = t >> 8;                   // 0..1
    int rb   = half << 5;                // 32 rows per half
    float a2 = 0.f; int prev = d_ids[rb]; bool firstrun = true;
    #pragma unroll
    for (int ii=0; ii<32; ii+=8){
      float v[8]; int dv[8];
      #pragma unroll
      for (int j=0;j<8;j++){
        int m_ = rb + ii + j;
        uint32_t byte = ((uint32_t)m_<<9) ^ ((uint32_t)col<<1) ^ ((uint32_t)(m_&7)<<4);
        v[j] = b2f(*(const u16*)((const char*)h_lds + byte));
        dv[j] = d_ids[m_];
      }
      #pragma unroll
      for (int j=0;j<8;j++){
        if (dv[j] != prev){
          float* p = &h_neigh[(size_t)prev*256 + col];
          if (firstrun) unsafeAtomicAdd(p, a2); else *p = a2;
          firstrun = false; a2 = v[j]; prev = dv[j];
        } else a2 += v[j];
      }
    }
    unsafeAtomicAdd(&h_neigh[(size_t)prev*256 + col], a2);
  }
}

// ---------------- node MLP ----------------
#define SILU_STORE2N() do { \
  _Pragma("unroll") for (int mi=0;mi<2;mi++) _Pragma("unroll") for (int ni=0;ni<4;ni++) \
  _Pragma("unroll") for (int j=0;j<4;j++){ \
    int m_ = mbase + mi*16 + l4*4 + j; int n_ = nbase + ni*16 + l15; \
    float v_ = silu_f(acc[mi][ni][j]); \
    uint32_t byte = ((uint32_t)m_<<9) ^ ((uint32_t)n_<<1) ^ ((uint32_t)(m_&7)<<4); \
    *(u16*)((char*)h_lds + byte) = f2b(v_); \
  } } while(0)

__global__ __launch_bounds__(512, 4) void node_mlp(
    const u16* __restrict__ node_feat, const float* __restrict__ h_neigh,
    const char* __restrict__ wsw, u16* __restrict__ hpre)
{
  __shared__ u16 h_lds[16384];           // 32KB: [64 rows][256] bf16, XOR-swizzled
  __shared__ float b1_l[256], b2_l[128];

  const int t = threadIdx.x, lane = t & 63, wid = t >> 6;
  const int mw = wid & 1, nw = wid >> 1;
  const int mbase = mw << 5, nbase = nw << 6;
  const int l15 = lane & 15, l4 = lane >> 4;
  const int tile = blockIdx.x;

  if (t < 256) b1_l[t] = ((const float*)(wsw+WS_B_N1))[t];
  if (t < 128) b2_l[t] = ((const float*)(wsw+WS_B_N2))[t];
  __syncthreads();

  const u16* Wt1 = (const u16*)(wsw + WS_WT_N1);   // [256][384]
  const u16* Wt2 = (const u16*)(wsw + WS_WT_N2);   // [128][256]

  f32x4 acc[2][4];
  #pragma unroll
  for (int mi=0;mi<2;mi++)
  #pragma unroll
  for (int ni=0;ni<4;ni++){ float b_ = b1_l[nbase+ni*16+l15]; acc[mi][ni] = (f32x4){b_,b_,b_,b_}; }

  // layer n1: K = 384 (128 node_feat bf16 | 256 h_neigh f32->bf16, vectorized)
  #pragma unroll
  for (int kk=0;kk<12;kk++){
    const int kel = kk*32 + l4*8;
    bf16x8 av[2];
    #pragma unroll
    for (int mi=0;mi<2;mi++){
      int row = tile*64 + mbase + mi*16 + l15;
      if (row >= N_NODES) row = 0;
      if (kk < 4){
        av[mi] = *(const bf16x8*)(node_feat + (size_t)row*128 + kel);
      } else {
        const float* hp = h_neigh + (size_t)row*256 + (kel - 128);
        f32x4 h0 = *(const f32x4*)(hp);
        f32x4 h1 = *(const f32x4*)(hp + 4);
        u16x8 u;
        #pragma unroll
        for (int e2=0;e2<4;e2++){ u[e2] = f2b(h0[e2]); u[e2+4] = f2b(h1[e2]); }
        av[mi] = __builtin_bit_cast(bf16x8, u);
      }
    }
    #pragma unroll
    for (int ni=0;ni<4;ni++){
      int n_ = nbase + ni*16 + l15;
      bf16x8 bv = *(const bf16x8*)(Wt1 + (size_t)n_*384 + kel);
      #pragma unroll
      for (int mi=0;mi<2;mi++)
        acc[mi][ni] = __builtin_amdgcn_mfma_f32_16x16x32_bf16(av[mi], bv, acc[mi][ni], 0,0,0);
    }
  }
  SILU_STORE2N();
  __syncthreads();

  // layer n2: K=256, N=128 (per wave: 32 cols), rows 0..63
  const int nb2 = nw << 5;
  f32x4 acc2[2][2];
  #pragma unroll
  for (int mi=0;mi<2;mi++)
  #pragma unroll
  for (int ni=0;ni<2;ni++){ float b_ = b2_l[nb2+ni*16+l15]; acc2[mi][ni] = (f32x4){b_,b_,b_,b_}; }
  #pragma unroll
  for (int kk=0;kk<8;kk++){
    const int kel = kk*32 + l4*8;
    bf16x8 av[2];
    #pragma unroll
    for (int mi=0;mi<2;mi++){
      int row = mbase + mi*16 + l15;
      uint32_t byte = ((uint32_t)row<<9) ^ ((uint32_t)kel<<1) ^ ((uint32_t)(row&7)<<4);
      av[mi] = *(const bf16x8*)((const char*)h_lds + byte);
    }
    #pragma unroll
    for (int ni=0;ni<2;ni++){
      int n_ = nb2 + ni*16 + l15;
      bf16x8 bv = *(const bf16x8*)(Wt2 + (size_t)n_*256 + kel);
      #pragma unroll
      for (int mi=0;mi<2;mi++)
        acc2[mi][ni] = __builtin_amdgcn_mfma_f32_16x16x32_bf16(av[mi], bv, acc2[mi][ni], 0,0,0);
    }
  }
  #pragma unroll
  for (int mi=0;mi<2;mi++)
  #pragma unroll
  for (int ni=0;ni<2;ni++)
  #pragma unroll
  for (int j=0;j<4;j++){
    int m_ = tile*64 + mbase + mi*16 + l4*4 + j;
    if (m_ < N_NODES){
      int n_ = nb2 + ni*16 + l15;
      hpre[(size_t)m_*128 + n_] = f2b(acc2[mi][ni][j]);
    }
  }
}

// ---------------- BatchNorm stats/final ----------------
__global__ void bn_stats_k(const u16* __restrict__ hpre, float* __restrict__ stat){
  int c = threadIdx.x;
  float s = 0.f, s2 = 0.f;
  for (int r = blockIdx.x; r < N_NODES; r += 256){
    float v = b2f(hpre[(size_t)r*128 + c]);
    s += v; s2 += v*v;
  }
  atomicAdd(&stat[c], s);
  atomicAdd(&stat[128+c], s2);
}

__global__ void bn_final_k(const float* __restrict__ stat, const char* __restrict__ wsw,
                           float* __restrict__ scale, float* __restrict__ shift){
  int c = threadIdx.x;
  if (c >= 128) return;
  float mu = stat[c] * (1.0f/N_NODES);
  float var = stat[128+c] * (1.0f/N_NODES) - mu*mu;
  float rs = rsqrtf(var + 1e-5f);
  float g = ((const float*)(wsw+WS_GAMMA))[c];
  float b = ((const float*)(wsw+WS_BETA))[c];
  scale[c] = rs*g;
  shift[c] = b - mu*rs*g;
}

// ---------------- fused finish: bn_apply | x_out ----------------
__global__ void finish_k(const u16* __restrict__ hpre, const float* __restrict__ scale,
                         const float* __restrict__ shift, const float* __restrict__ coord,
                         const int* __restrict__ deg, const float* __restrict__ xsum,
                         void* __restrict__ d_out, const int* __restrict__ flagp)
{
  const int b = blockIdx.x;
  const int fl = *flagp;
  if (b < 3125){
    int i = b*256 + threadIdx.x;
    if (i >= N_NODES*128/8) return;
    u16x8 v = *(const u16x8*)(hpre + (size_t)i*8);
    int c0 = (i*8) & 127;
    if (fl){
      float* o = (float*)d_out + (size_t)i*8;
      #pragma unroll
      for (int j=0;j<8;j++) o[j] = b2f(v[j])*scale[c0+j] + shift[c0+j];
    } else {
      u16x8 w;
      #pragma unroll
      for (int j=0;j<8;j++) w[j] = f2b(b2f(v[j])*scale[c0+j] + shift[c0+j]);
      *(u16x8*)((u16*)d_out + (size_t)i*8) = w;
    }
    return;
  }
  {
    int n = (b-3125)*256 + threadIdx.x;
    if (n >= N_NODES) return;
    float dm = fmaxf((float)deg[n], 1.f);
    float v0 = coord[n*3+0] + xsum[n*3+0]/dm;
    float v1 = coord[n*3+1] + xsum[n*3+1]/dm;
    float v2 = coord[n*3+2] + xsum[n*3+2]/dm;
    const size_t base = (size_t)N_NODES*128 + (size_t)n*3;
    if (fl){
      float* o = (float*)d_out;
      o[base+0]=v0; o[base+1]=v1; o[base+2]=v2;
    } else {
      u16* o = (u16*)d_out;
      o[base+0]=f2b(v0); o[base+1]=f2b(v1); o[base+2]=f2b(v2);
    }
  }
}

// ---------------- launch ----------------
extern "C" void kernel_launch(void* const* d_in, const int* in_sizes, int n_in,
                              void* d_out, int out_size, void* d_ws, size_t ws_size,
                              hipStream_t stream)
{
  const void* node_feat_raw = d_in[0];
  const void* coord_raw     = d_in[1];
  const int* src       = (const int*)d_in[2];
  const int* dst       = (const int*)d_in[3];
  char* ws = (char*)d_ws;

  int*   flag  = (int*)(ws + WS_FLAG);
  int*   deg   = (int*)(ws + WS_DEG);
  int*   off   = (int*)(ws + WS_OFF);
  int*   bsum  = (int*)(ws + WS_BSUM);
  int*   bpre  = (int*)(ws + WS_BPRE);
  int*   cur   = (int*)(ws + WS_CUR);
  int*   eid   = (int*)(ws + WS_EID);
  float* xsum  = (float*)(ws + WS_XSUM);
  float* hn    = (float*)(ws + WS_HN);
  u16*   pa    = (u16*)(ws + WS_PA);
  u16*   pb    = (u16*)(ws + WS_PB);
  u16*   hpre  = (u16*)(ws + WS_PA);   // aliases pa (dead after edge phase)
  const u16*   nfc = (const u16*)(ws + WS_NF);
  const float* cfc = (const float*)(ws + WS_CF);
  float* stat  = (float*)(ws + WS_STAT);
  float* scale = (float*)(ws + WS_SCALE);
  float* shift = (float*)(ws + WS_SHIFT);

  const bool pre = (ws_size >= (size_t)WS_PRE_END);

  hipMemsetAsync(deg, 0, N_NODES*sizeof(int), stream);
  hipMemsetAsync(xsum, 0, N_NODES*3*sizeof(float), stream);
  hipMemsetAsync(hn, 0, (size_t)N_NODES*256*sizeof(float), stream);
  hipMemsetAsync(stat, 0, 256*sizeof(float), stream);

  detect_k<<<1,64,0,stream>>>(node_feat_raw, flag);
  prep_all_k<<<11250,256,0,stream>>>(node_feat_raw, coord_raw,
                                     d_in[4],d_in[5],d_in[6],d_in[7],d_in[8],d_in[9],
                                     d_in[10],d_in[11],d_in[12],d_in[13],d_in[14],
                                     d_in[15],d_in[16], dst, deg, ws, flag);
  scanA_k<<<196,256,0,stream>>>(deg, off, bsum);
  scanB_k<<<1,256,0,stream>>>(bsum, bpre, off);
  scanC_k<<<196,256,0,stream>>>(deg, off, bpre, cur);
  scatter_k<<<3125,256,0,stream>>>(dst, cur, eid);

  if (pre){
    pab_k<<<782,512,0,stream>>>(nfc, ws, pa, pb);
    edge_mlp<true><<<12500,512,0,stream>>>(nfc, cfc, src, dst, ws, eid, pa, pb, hn, xsum);
  } else {
    edge_mlp<false><<<12500,512,0,stream>>>(nfc, cfc, src, dst, ws, eid, pa, pb, hn, xsum);
  }

  node_mlp<<<782,512,0,stream>>>(nfc, hn, ws, hpre);
  bn_stats_k<<<256,128,0,stream>>>(hpre, stat);
  bn_final_k<<<1,128,0,stream>>>(stat, ws, scale, shift);
  finish_k<<<3321,256,0,stream>>>(hpre, scale, shift, cfc, deg, xsum, d_out, flag);
}